// Round 2
// baseline (517.583 us; speedup 1.0000x reference)
//
#include <hip/hip_runtime.h>
#include <hip/hip_bf16.h>

// Problem constants
#define B_   4
#define T_   2048
#define C_   1024
#define H_   16
#define HD_  64
#define BH_  (B_*H_)    // 64
#define M_   (B_*T_)    // 8192
#define N1_  (3*C_)     // 3072

typedef __hip_bfloat16 bf16;
typedef __attribute__((ext_vector_type(8))) __bf16 bf16x8v;   // MFMA A/B frag (4 VGPRs)
typedef __attribute__((ext_vector_type(4))) float  f32x4;     // MFMA C/D frag

__device__ __forceinline__ f32x4 mfma16(bf16x8v a, bf16x8v b, f32x4 c) {
    return __builtin_amdgcn_mfma_f32_16x16x32_bf16(a, b, c, 0, 0, 0);
}

// ---------------------------------------------------------------------------
// Tiled transpose + fp32->bf16 convert: out[n][k] = bf16(in[k][n]).
// in is fp32 [K][N] row-major. 32x32 tiles, 256 threads.
// ---------------------------------------------------------------------------
__global__ void transpose_f32_to_bf16(const float* __restrict__ in,
                                      bf16* __restrict__ out, int K, int N) {
    __shared__ float t[32][33];
    const int n0 = blockIdx.x * 32, k0 = blockIdx.y * 32;
    const int c  = threadIdx.x & 31;       // fast index
    const int rr = threadIdx.x >> 5;       // 0..7
#pragma unroll
    for (int i = 0; i < 4; ++i)            // read coalesced along n
        t[c][rr + 8*i] = in[(size_t)(k0 + rr + 8*i) * N + n0 + c];
    __syncthreads();
#pragma unroll
    for (int i = 0; i < 4; ++i)            // write coalesced along k
        out[(size_t)(n0 + rr + 8*i) * K + k0 + c] = __float2bfloat16(t[rr + 8*i][c]);
}

// ---------------------------------------------------------------------------
// GEMM  C[M,N] = A[M,K] @ B[K,N], with B supplied TRANSPOSED as bf16 Bt[N][K].
// A is fp32 (AF32=true, converted to bf16 during staging) or bf16.
// 128x128 tile / block, 256 threads = 4 waves in 2x2, each wave 64x64
// (4x4 MFMA 16x16x32 C-frags). BK=32. LDS rows padded 32->40 elems.
// EPI=0: fp32 store to Cmat.
// EPI=1: qkv scatter epilogue: col<1024 -> Q (scaled 0.125, [bh][t][d]),
//        col<2048 -> K ([bh][t][d]), else V transposed ([bh][d][t]).
// ---------------------------------------------------------------------------
#define BKP 40

template<int EPI, bool AF32>
__global__ __launch_bounds__(256, 2)
void gemm_bt(const void* __restrict__ Araw, const bf16* __restrict__ Bt,
             float* __restrict__ Cmat, int N, int K,
             bf16* __restrict__ qb, bf16* __restrict__ kb, bf16* __restrict__ vb)
{
    __shared__ bf16 Alds[128][BKP];   // 10 KB
    __shared__ bf16 Blds[128][BKP];   // 10 KB

    const int tid  = threadIdx.x;
    const int wave = tid >> 6, lane = tid & 63;
    const int quad = lane >> 4, l16 = lane & 15;
    const int wm   = (wave >> 1) * 64, wn = (wave & 1) * 64;
    const size_t row0 = (size_t)blockIdx.y * 128;
    const size_t col0 = (size_t)blockIdx.x * 128;

    const f32x4 z4 = {0.f, 0.f, 0.f, 0.f};
    f32x4 acc[4][4];
#pragma unroll
    for (int mi = 0; mi < 4; ++mi)
#pragma unroll
        for (int ni = 0; ni < 4; ++ni) acc[mi][ni] = z4;

    // staging decomposition: each thread covers rows {r_a, r_a+64}, cols ck..ck+7
    const int r_a = tid >> 2;          // 0..63
    const int ck  = (tid & 3) * 8;     // 0,8,16,24

    const float* aF0 = (const float*)Araw + (row0 + r_a)      * K + ck;
    const float* aF1 = (const float*)Araw + (row0 + r_a + 64) * K + ck;
    const bf16*  aB0 = (const bf16*) Araw + (row0 + r_a)      * K + ck;
    const bf16*  aB1 = (const bf16*) Araw + (row0 + r_a + 64) * K + ck;
    const bf16*  bp0 = Bt + (col0 + r_a)      * K + ck;
    const bf16*  bp1 = Bt + (col0 + r_a + 64) * K + ck;

    for (int k0 = 0; k0 < K; k0 += 32) {
        bf16 t0[8], t1[8];
        if constexpr (AF32) {
            float f0[8], f1[8];
            *(float4*)(f0)     = *(const float4*)(aF0 + k0);
            *(float4*)(f0 + 4) = *(const float4*)(aF0 + k0 + 4);
            *(float4*)(f1)     = *(const float4*)(aF1 + k0);
            *(float4*)(f1 + 4) = *(const float4*)(aF1 + k0 + 4);
#pragma unroll
            for (int j = 0; j < 8; ++j) { t0[j] = __float2bfloat16(f0[j]); t1[j] = __float2bfloat16(f1[j]); }
        } else {
            *(uint4*)(t0) = *(const uint4*)(aB0 + k0);
            *(uint4*)(t1) = *(const uint4*)(aB1 + k0);
        }
        const uint4 b0 = *(const uint4*)(bp0 + k0);
        const uint4 b1 = *(const uint4*)(bp1 + k0);
        *(uint4*)(&Alds[r_a][ck])      = *(uint4*)(t0);
        *(uint4*)(&Alds[r_a + 64][ck]) = *(uint4*)(t1);
        *(uint4*)(&Blds[r_a][ck])      = b0;
        *(uint4*)(&Blds[r_a + 64][ck]) = b1;
        __syncthreads();

        bf16x8v af[4], bfr[4];
#pragma unroll
        for (int i = 0; i < 4; ++i) {
            af[i]  = *(const bf16x8v*)(&Alds[wm + i*16 + l16][quad*8]);
            bfr[i] = *(const bf16x8v*)(&Blds[wn + i*16 + l16][quad*8]);
        }
#pragma unroll
        for (int mi = 0; mi < 4; ++mi)
#pragma unroll
            for (int ni = 0; ni < 4; ++ni)
                acc[mi][ni] = mfma16(af[mi], bfr[ni], acc[mi][ni]);
        __syncthreads();   // protect LDS from next iteration's staging
    }

    // epilogue: C/D layout row=(quad*4+r), col=l16 within each 16x16 frag
#pragma unroll
    for (int mi = 0; mi < 4; ++mi) {
        const size_t rowb = row0 + wm + mi*16 + quad*4;
#pragma unroll
        for (int ni = 0; ni < 4; ++ni) {
            const size_t col = col0 + wn + ni*16 + l16;
#pragma unroll
            for (int r = 0; r < 4; ++r) {
                const float v = acc[mi][ni][r];
                if constexpr (EPI == 0) {
                    Cmat[(rowb + r) * N + col] = v;
                } else {
                    const int rowi = (int)(rowb + r);
                    const int b  = rowi >> 11;          // /T_
                    const int t  = rowi & (T_ - 1);
                    const int coli = (int)col;
                    const int type = coli >> 10;        // 0=q 1=k 2=v
                    const int cc2  = coli & (C_ - 1);
                    const int h = cc2 >> 6, d = cc2 & (HD_ - 1);
                    const int bh = b * H_ + h;
                    if (type == 0)
                        qb[((size_t)bh * T_ + t) * HD_ + d] = __float2bfloat16(v * 0.125f);
                    else if (type == 1)
                        kb[((size_t)bh * T_ + t) * HD_ + d] = __float2bfloat16(v);
                    else
                        vb[((size_t)bh * HD_ + d) * T_ + t] = __float2bfloat16(v);
                }
            }
        }
    }
}

// ---------------------------------------------------------------------------
// Flash attention (causal), bf16 in/out, fp32 online softmax.
// grid = (T/64, B*H); block 256 = 4 waves, each wave owns 16 Q-rows.
// Key chunks of 32 staged in LDS (K[32][64], Vt[64][32], both padded).
// Q pre-scaled by 1/sqrt(64) in the QKV-GEMM epilogue.
// ---------------------------------------------------------------------------
#define KP 72   // 64+8 pad
#define VP 40   // 32+8 pad
#define PP 40

__global__ __launch_bounds__(256, 2)
void attn_fused(const bf16* __restrict__ qb, const bf16* __restrict__ kb,
                const bf16* __restrict__ vb, bf16* __restrict__ attn)
{
    __shared__ bf16 Klds[32][KP];        // 4.5 KB
    __shared__ bf16 Vlds[64][VP];        // 5 KB
    __shared__ bf16 Plds[4][16][PP];     // 5 KB  (per-wave P round-trip)

    const int tid  = threadIdx.x;
    const int wave = tid >> 6, lane = tid & 63;
    const int quad = lane >> 4, l16 = lane & 15;
    const int bh   = blockIdx.y;
    const int q0b  = blockIdx.x * 64;
    const int q0w  = q0b + wave * 16;

    const bf16* Q  = qb + (size_t)bh * T_ * HD_;
    const bf16* Kp = kb + (size_t)bh * T_ * HD_;
    const bf16* Vp = vb + (size_t)bh * HD_ * T_;

    // Q fragments: A-op layout m=l16 (row), k=quad*8+j (d); two k-parts for d=64
    const bf16x8v qf0 = *(const bf16x8v*)(Q + (size_t)(q0w + l16) * HD_ + quad*8);
    const bf16x8v qf1 = *(const bf16x8v*)(Q + (size_t)(q0w + l16) * HD_ + 32 + quad*8);

    const f32x4 z4 = {0.f, 0.f, 0.f, 0.f};
    f32x4 o[4]; // O[16 rows][64 d] : 4 d-tiles of C-frags
#pragma unroll
    for (int ni = 0; ni < 4; ++ni) o[ni] = z4;
    float m_r[4], l_r[4];
#pragma unroll
    for (int r = 0; r < 4; ++r) { m_r[r] = -3.0e38f; l_r[r] = 0.f; }

    const int kr = tid >> 3, kc = (tid & 7) * 8;   // K staging: 32x64
    const int vr = tid >> 2, vc = (tid & 3) * 8;   // V staging: 64x32

    const int kend = q0b + 64;
    for (int k0 = 0; k0 < kend; k0 += 32) {
        __syncthreads();   // all prior reads of K/V LDS done
        *(uint4*)(&Klds[kr][kc]) = *(const uint4*)(Kp + (size_t)(k0 + kr) * HD_ + kc);
        *(uint4*)(&Vlds[vr][vc]) = *(const uint4*)(Vp + (size_t)vr * T_ + k0 + vc);
        __syncthreads();

        if (k0 <= q0w + 15) {   // wave-uniform causal skip
            // ---- S = Q K^T  (two 16-key n-tiles) ----
            f32x4 s0 = z4, s1 = z4;
#pragma unroll
            for (int kp = 0; kp < 2; ++kp) {
                const bf16x8v aq = kp ? qf1 : qf0;
                const bf16x8v b0 = *(const bf16x8v*)(&Klds[l16][kp*32 + quad*8]);
                const bf16x8v b1 = *(const bf16x8v*)(&Klds[16 + l16][kp*32 + quad*8]);
                s0 = mfma16(aq, b0, s0);
                s1 = mfma16(aq, b1, s1);
            }
            // ---- causal mask (only near diagonal) ----
            if (k0 + 31 > q0w) {
#pragma unroll
                for (int r = 0; r < 4; ++r) {
                    const int row = q0w + quad*4 + r;
                    if (k0 + l16      > row) s0[r] = -3.0e38f;
                    if (k0 + 16 + l16 > row) s1[r] = -3.0e38f;
                }
            }
            // ---- online softmax (rows live in 16-lane groups) ----
            float pe0[4], pe1[4];
#pragma unroll
            for (int r = 0; r < 4; ++r) {
                float mx = fmaxf(s0[r], s1[r]);
                mx = fmaxf(mx, __shfl_xor(mx, 1, 16));
                mx = fmaxf(mx, __shfl_xor(mx, 2, 16));
                mx = fmaxf(mx, __shfl_xor(mx, 4, 16));
                mx = fmaxf(mx, __shfl_xor(mx, 8, 16));
                const float mnew  = fmaxf(m_r[r], mx);
                const float alpha = __expf(m_r[r] - mnew);
                const float e0 = __expf(s0[r] - mnew);
                const float e1 = __expf(s1[r] - mnew);
                float rsum = e0 + e1;
                rsum += __shfl_xor(rsum, 1, 16);
                rsum += __shfl_xor(rsum, 2, 16);
                rsum += __shfl_xor(rsum, 4, 16);
                rsum += __shfl_xor(rsum, 8, 16);
                l_r[r] = l_r[r] * alpha + rsum;
                m_r[r] = mnew;
#pragma unroll
                for (int ni = 0; ni < 4; ++ni) o[ni][r] *= alpha;
                pe0[r] = e0; pe1[r] = e1;
            }
            // ---- P: C-layout -> A-layout via per-wave LDS round-trip ----
#pragma unroll
            for (int r = 0; r < 4; ++r) {
                Plds[wave][quad*4 + r][l16]      = __float2bfloat16(pe0[r]);
                Plds[wave][quad*4 + r][16 + l16] = __float2bfloat16(pe1[r]);
            }
            const bf16x8v pa = *(const bf16x8v*)(&Plds[wave][l16][quad*8]);
            // ---- O += P V ----
#pragma unroll
            for (int ni = 0; ni < 4; ++ni) {
                const bf16x8v bv = *(const bf16x8v*)(&Vlds[ni*16 + l16][quad*8]);
                o[ni] = mfma16(pa, bv, o[ni]);
            }
        }
    }

    // epilogue: attn[b][t][h*64+d], normalize by l
    const int b = bh >> 4, h = bh & (H_ - 1);
#pragma unroll
    for (int r = 0; r < 4; ++r) {
        const float inv = 1.0f / l_r[r];
        const int t = q0w + quad*4 + r;
        const size_t base = ((size_t)(b * T_ + t)) * C_ + h * HD_;
#pragma unroll
        for (int ni = 0; ni < 4; ++ni)
            attn[base + ni*16 + l16] = __float2bfloat16(o[ni][r] * inv);
    }
}

// ---------------------------------------------------------------------------
// Workspace layout (bytes from d_ws):
//   [ 0,16M)  q   bf16 [64][2048][64]   (pre-scaled by 0.125)
//   [16,32M)  k   bf16 [64][2048][64]
//   [32,48M)  v   bf16 [64][64][2048]   (transposed: [bh][d][t])
//   [48,64M)  attn bf16 [8192][1024]
//   [64,70M)  wt_qkv bf16 [3072][1024]
//   [70,72M)  wt_out bf16 [1024][1024]
// Total 72 MB.
// ---------------------------------------------------------------------------
extern "C" void kernel_launch(void* const* d_in, const int* in_sizes, int n_in,
                              void* d_out, int out_size, void* d_ws, size_t ws_size,
                              hipStream_t stream)
{
    const float* x     = (const float*)d_in[0];
    const float* w_qkv = (const float*)d_in[1];
    const float* w_out = (const float*)d_in[2];
    float* out = (float*)d_out;

    char* ws = (char*)d_ws;
    bf16* qb     = (bf16*)(ws);
    bf16* kb     = (bf16*)(ws + (size_t)16 * 1024 * 1024);
    bf16* vb     = (bf16*)(ws + (size_t)32 * 1024 * 1024);
    bf16* attnb  = (bf16*)(ws + (size_t)48 * 1024 * 1024);
    bf16* wtqkv  = (bf16*)(ws + (size_t)64 * 1024 * 1024);
    bf16* wtout  = (bf16*)(ws + (size_t)70 * 1024 * 1024);

    // 1) transpose+convert weights to bf16 [N][K]
    transpose_f32_to_bf16<<<dim3(N1_/32, C_/32), 256, 0, stream>>>(w_qkv, wtqkv, C_, N1_);
    transpose_f32_to_bf16<<<dim3(C_/32,  C_/32), 256, 0, stream>>>(w_out, wtout, C_, C_);

    // 2) qkv = x @ w_qkv, scatter into q/k/v layouts (q pre-scaled)
    gemm_bt<1, true><<<dim3(N1_/128, M_/128), 256, 0, stream>>>(
        (const void*)x, wtqkv, nullptr, N1_, C_, qb, kb, vb);

    // 3) causal flash attention
    attn_fused<<<dim3(T_/64, BH_), 256, 0, stream>>>(qb, kb, vb, attnb);

    // 4) out = attn @ w_out (fp32 store)
    gemm_bt<0, false><<<dim3(C_/128, M_/128), 256, 0, stream>>>(
        (const void*)attnb, wtout, out, C_, C_, nullptr, nullptr, nullptr);
}

// Round 3
// 414.679 us; speedup vs baseline: 1.2482x; 1.2482x over previous
//
#include <hip/hip_runtime.h>
#include <hip/hip_bf16.h>

// Problem constants
#define B_   4
#define T_   2048
#define C_   1024
#define H_   16
#define HD_  64
#define BH_  (B_*H_)    // 64
#define M_   (B_*T_)    // 8192
#define N1_  (3*C_)     // 3072

typedef __hip_bfloat16 bf16;
typedef __attribute__((ext_vector_type(8))) __bf16 bf16x8v;   // MFMA A/B frag (4 VGPRs)
typedef __attribute__((ext_vector_type(4))) float  f32x4;     // MFMA C/D frag

__device__ __forceinline__ f32x4 mfma16(bf16x8v a, bf16x8v b, f32x4 c) {
    return __builtin_amdgcn_mfma_f32_16x16x32_bf16(a, b, c, 0, 0, 0);
}

// ---------------------------------------------------------------------------
// Tiled transpose + fp32->bf16 convert: out[n][k] = bf16(in[k][n]).
// ---------------------------------------------------------------------------
__global__ void transpose_f32_to_bf16(const float* __restrict__ in,
                                      bf16* __restrict__ out, int K, int N) {
    __shared__ float t[32][33];
    const int n0 = blockIdx.x * 32, k0 = blockIdx.y * 32;
    const int c  = threadIdx.x & 31;
    const int rr = threadIdx.x >> 5;
#pragma unroll
    for (int i = 0; i < 4; ++i)
        t[c][rr + 8*i] = in[(size_t)(k0 + rr + 8*i) * N + n0 + c];
    __syncthreads();
#pragma unroll
    for (int i = 0; i < 4; ++i)
        out[(size_t)(n0 + rr + 8*i) * K + k0 + c] = __float2bfloat16(t[rr + 8*i][c]);
}

// ---------------------------------------------------------------------------
// GEMM  C[M,N] = A[M,K] @ bf16 Bt[N][K] (B pre-transposed).
// 128x128 tile, 256 threads = 4 waves 2x2, 4x4 MFMA frags/wave, BK=32.
// (unchanged from round-2 passing version)
// ---------------------------------------------------------------------------
#define BKP 40

template<int EPI, bool AF32>
__global__ __launch_bounds__(256, 2)
void gemm_bt(const void* __restrict__ Araw, const bf16* __restrict__ Bt,
             float* __restrict__ Cmat, int N, int K,
             bf16* __restrict__ qb, bf16* __restrict__ kb, bf16* __restrict__ vb)
{
    __shared__ bf16 Alds[128][BKP];
    __shared__ bf16 Blds[128][BKP];

    const int tid  = threadIdx.x;
    const int wave = tid >> 6, lane = tid & 63;
    const int quad = lane >> 4, l16 = lane & 15;
    const int wm   = (wave >> 1) * 64, wn = (wave & 1) * 64;
    const size_t row0 = (size_t)blockIdx.y * 128;
    const size_t col0 = (size_t)blockIdx.x * 128;

    const f32x4 z4 = {0.f, 0.f, 0.f, 0.f};
    f32x4 acc[4][4];
#pragma unroll
    for (int mi = 0; mi < 4; ++mi)
#pragma unroll
        for (int ni = 0; ni < 4; ++ni) acc[mi][ni] = z4;

    const int r_a = tid >> 2;
    const int ck  = (tid & 3) * 8;

    const float* aF0 = (const float*)Araw + (row0 + r_a)      * K + ck;
    const float* aF1 = (const float*)Araw + (row0 + r_a + 64) * K + ck;
    const bf16*  aB0 = (const bf16*) Araw + (row0 + r_a)      * K + ck;
    const bf16*  aB1 = (const bf16*) Araw + (row0 + r_a + 64) * K + ck;
    const bf16*  bp0 = Bt + (col0 + r_a)      * K + ck;
    const bf16*  bp1 = Bt + (col0 + r_a + 64) * K + ck;

    for (int k0 = 0; k0 < K; k0 += 32) {
        bf16 t0[8], t1[8];
        if constexpr (AF32) {
            float f0[8], f1[8];
            *(float4*)(f0)     = *(const float4*)(aF0 + k0);
            *(float4*)(f0 + 4) = *(const float4*)(aF0 + k0 + 4);
            *(float4*)(f1)     = *(const float4*)(aF1 + k0);
            *(float4*)(f1 + 4) = *(const float4*)(aF1 + k0 + 4);
#pragma unroll
            for (int j = 0; j < 8; ++j) { t0[j] = __float2bfloat16(f0[j]); t1[j] = __float2bfloat16(f1[j]); }
        } else {
            *(uint4*)(t0) = *(const uint4*)(aB0 + k0);
            *(uint4*)(t1) = *(const uint4*)(aB1 + k0);
        }
        const uint4 b0 = *(const uint4*)(bp0 + k0);
        const uint4 b1 = *(const uint4*)(bp1 + k0);
        *(uint4*)(&Alds[r_a][ck])      = *(uint4*)(t0);
        *(uint4*)(&Alds[r_a + 64][ck]) = *(uint4*)(t1);
        *(uint4*)(&Blds[r_a][ck])      = b0;
        *(uint4*)(&Blds[r_a + 64][ck]) = b1;
        __syncthreads();

        bf16x8v af[4], bfr[4];
#pragma unroll
        for (int i = 0; i < 4; ++i) {
            af[i]  = *(const bf16x8v*)(&Alds[wm + i*16 + l16][quad*8]);
            bfr[i] = *(const bf16x8v*)(&Blds[wn + i*16 + l16][quad*8]);
        }
#pragma unroll
        for (int mi = 0; mi < 4; ++mi)
#pragma unroll
            for (int ni = 0; ni < 4; ++ni)
                acc[mi][ni] = mfma16(af[mi], bfr[ni], acc[mi][ni]);
        __syncthreads();
    }

#pragma unroll
    for (int mi = 0; mi < 4; ++mi) {
        const size_t rowb = row0 + wm + mi*16 + quad*4;
#pragma unroll
        for (int ni = 0; ni < 4; ++ni) {
            const size_t col = col0 + wn + ni*16 + l16;
#pragma unroll
            for (int r = 0; r < 4; ++r) {
                const float v = acc[mi][ni][r];
                if constexpr (EPI == 0) {
                    Cmat[(rowb + r) * N + col] = v;
                } else {
                    const int rowi = (int)(rowb + r);
                    const int b  = rowi >> 11;
                    const int t  = rowi & (T_ - 1);
                    const int coli = (int)col;
                    const int type = coli >> 10;
                    const int cc2  = coli & (C_ - 1);
                    const int h = cc2 >> 6, d = cc2 & (HD_ - 1);
                    const int bh = b * H_ + h;
                    if (type == 0)
                        qb[((size_t)bh * T_ + t) * HD_ + d] = __float2bfloat16(v * 0.125f);
                    else if (type == 1)
                        kb[((size_t)bh * T_ + t) * HD_ + d] = __float2bfloat16(v);
                    else
                        vb[((size_t)bh * HD_ + d) * T_ + t] = __float2bfloat16(v);
                }
            }
        }
    }
}

// ---------------------------------------------------------------------------
// Flash attention v2 (causal), bf16 MFMA, fp32 online softmax.
// grid = (T/128, B*H) with HEAVY-FIRST qi mapping; block 256 = 4 waves.
// Each wave owns 32 Q rows (2 m-frags); KV chunk = 64 keys.
// Register-prefetch of next chunk's K/V overlaps global latency with compute.
// 32 MFMAs per wave per chunk (vs 8 in v1); 4x fewer barriers.
// ---------------------------------------------------------------------------
#define KP 72   // 64+8
#define VP 72
#define PP 72

__global__ __launch_bounds__(256, 3)
void attn_fused(const bf16* __restrict__ qb, const bf16* __restrict__ kb,
                const bf16* __restrict__ vb, bf16* __restrict__ attn)
{
    __shared__ bf16 Klds[64][KP];        // 9.2 KB   K[key][d]
    __shared__ bf16 Vlds[64][VP];        // 9.2 KB   V[d][key]
    __shared__ bf16 Plds[4][32][PP];     // 18.4 KB  per-wave P round-trip

    const int tid  = threadIdx.x;
    const int wave = tid >> 6, lane = tid & 63;
    const int quad = lane >> 4, l16 = lane & 15;
    const int bh   = blockIdx.y;
    const int qi   = (gridDim.x - 1) - blockIdx.x;   // heavy blocks dispatch first
    const int q0b  = qi * 128;
    const int q0w  = q0b + wave * 32;

    const bf16* Q  = qb + (size_t)bh * T_ * HD_;
    const bf16* Kp = kb + (size_t)bh * T_ * HD_;
    const bf16* Vp = vb + (size_t)bh * HD_ * T_;

    // Q fragments [mi][kp]: A-op layout m=l16, k=quad*8+j
    bf16x8v qf[2][2];
#pragma unroll
    for (int mi = 0; mi < 2; ++mi)
#pragma unroll
        for (int kp = 0; kp < 2; ++kp)
            qf[mi][kp] = *(const bf16x8v*)(Q + (size_t)(q0w + mi*16 + l16) * HD_ + kp*32 + quad*8);

    const f32x4 z4 = {0.f, 0.f, 0.f, 0.f};
    f32x4 o[2][4];
#pragma unroll
    for (int mi = 0; mi < 2; ++mi)
#pragma unroll
        for (int di = 0; di < 4; ++di) o[mi][di] = z4;
    float m_r[2][4], l_r[2][4];
#pragma unroll
    for (int mi = 0; mi < 2; ++mi)
#pragma unroll
        for (int r = 0; r < 4; ++r) { m_r[mi][r] = -3.0e38f; l_r[mi][r] = 0.f; }

    // staging: thread covers K rows {kr, kr+32} cols kc..kc+7; same for V (d-major)
    const int kr = tid >> 3;          // 0..31
    const int kc = (tid & 7) * 8;     // 0..56

    const int kend = q0b + 128;

    // preload chunk 0
    uint4 kreg0 = *(const uint4*)(Kp + (size_t)kr        * HD_ + kc);
    uint4 kreg1 = *(const uint4*)(Kp + (size_t)(kr + 32) * HD_ + kc);
    uint4 vreg0 = *(const uint4*)(Vp + (size_t)kr        * T_  + kc);
    uint4 vreg1 = *(const uint4*)(Vp + (size_t)(kr + 32) * T_  + kc);

    for (int k0 = 0; k0 < kend; k0 += 64) {
        __syncthreads();   // prior chunk's LDS reads complete
        *(uint4*)(&Klds[kr][kc])      = kreg0;
        *(uint4*)(&Klds[kr + 32][kc]) = kreg1;
        *(uint4*)(&Vlds[kr][kc])      = vreg0;
        *(uint4*)(&Vlds[kr + 32][kc]) = vreg1;
        __syncthreads();

        // prefetch next chunk into registers (in flight during compute)
        const int kn = (k0 + 64 < kend) ? (k0 + 64) : k0;
        kreg0 = *(const uint4*)(Kp + (size_t)(kn + kr)      * HD_ + kc);
        kreg1 = *(const uint4*)(Kp + (size_t)(kn + kr + 32) * HD_ + kc);
        vreg0 = *(const uint4*)(Vp + (size_t)kr        * T_ + kn + kc);
        vreg1 = *(const uint4*)(Vp + (size_t)(kr + 32) * T_ + kn + kc);

        if (k0 <= q0w + 31) {   // wave-uniform causal skip
            // ---- S = Q K^T : 2 m-tiles x 4 n-tiles ----
            f32x4 s[2][4];
#pragma unroll
            for (int mi = 0; mi < 2; ++mi)
#pragma unroll
                for (int ni = 0; ni < 4; ++ni) s[mi][ni] = z4;
#pragma unroll
            for (int kp = 0; kp < 2; ++kp) {
#pragma unroll
                for (int ni = 0; ni < 4; ++ni) {
                    const bf16x8v kf = *(const bf16x8v*)(&Klds[ni*16 + l16][kp*32 + quad*8]);
                    s[0][ni] = mfma16(qf[0][kp], kf, s[0][ni]);
                    s[1][ni] = mfma16(qf[1][kp], kf, s[1][ni]);
                }
            }
            // ---- causal mask (only chunks near the diagonal) ----
            if (k0 + 63 > q0w) {
#pragma unroll
                for (int mi = 0; mi < 2; ++mi)
#pragma unroll
                    for (int r = 0; r < 4; ++r) {
                        const int row = q0w + mi*16 + quad*4 + r;
#pragma unroll
                        for (int ni = 0; ni < 4; ++ni)
                            if (k0 + ni*16 + l16 > row) s[mi][ni][r] = -3.0e38f;
                    }
            }
            // ---- online softmax (row lives across 16 lanes, 4 vals/lane) ----
#pragma unroll
            for (int mi = 0; mi < 2; ++mi) {
#pragma unroll
                for (int r = 0; r < 4; ++r) {
                    float mx = fmaxf(fmaxf(s[mi][0][r], s[mi][1][r]),
                                     fmaxf(s[mi][2][r], s[mi][3][r]));
                    mx = fmaxf(mx, __shfl_xor(mx, 1, 16));
                    mx = fmaxf(mx, __shfl_xor(mx, 2, 16));
                    mx = fmaxf(mx, __shfl_xor(mx, 4, 16));
                    mx = fmaxf(mx, __shfl_xor(mx, 8, 16));
                    const float mnew  = fmaxf(m_r[mi][r], mx);
                    const float alpha = __expf(m_r[mi][r] - mnew);
                    float e[4];
#pragma unroll
                    for (int ni = 0; ni < 4; ++ni) e[ni] = __expf(s[mi][ni][r] - mnew);
                    float rsum = (e[0] + e[1]) + (e[2] + e[3]);
                    rsum += __shfl_xor(rsum, 1, 16);
                    rsum += __shfl_xor(rsum, 2, 16);
                    rsum += __shfl_xor(rsum, 4, 16);
                    rsum += __shfl_xor(rsum, 8, 16);
                    l_r[mi][r] = l_r[mi][r] * alpha + rsum;
                    m_r[mi][r] = mnew;
#pragma unroll
                    for (int di = 0; di < 4; ++di) o[mi][di][r] *= alpha;
                    const int prow = mi*16 + quad*4 + r;
#pragma unroll
                    for (int ni = 0; ni < 4; ++ni)
                        Plds[wave][prow][ni*16 + l16] = __float2bfloat16(e[ni]);
                }
            }
            // ---- O += P V : 2 m-tiles x 4 d-tiles x 2 k-parts ----
#pragma unroll
            for (int kp = 0; kp < 2; ++kp) {
                const bf16x8v pa0 = *(const bf16x8v*)(&Plds[wave][l16][kp*32 + quad*8]);
                const bf16x8v pa1 = *(const bf16x8v*)(&Plds[wave][16 + l16][kp*32 + quad*8]);
#pragma unroll
                for (int di = 0; di < 4; ++di) {
                    const bf16x8v vf = *(const bf16x8v*)(&Vlds[di*16 + l16][kp*32 + quad*8]);
                    o[0][di] = mfma16(pa0, vf, o[0][di]);
                    o[1][di] = mfma16(pa1, vf, o[1][di]);
                }
            }
        }
    }

    // epilogue: attn[b][t][h*64+d], normalize by l
    const int b = bh >> 4, h = bh & (H_ - 1);
#pragma unroll
    for (int mi = 0; mi < 2; ++mi) {
#pragma unroll
        for (int r = 0; r < 4; ++r) {
            const float inv = 1.0f / l_r[mi][r];
            const int t = q0w + mi*16 + quad*4 + r;
            const size_t base = ((size_t)(b * T_ + t)) * C_ + h * HD_;
#pragma unroll
            for (int di = 0; di < 4; ++di)
                attn[base + di*16 + l16] = __float2bfloat16(o[mi][di][r] * inv);
        }
    }
}

// ---------------------------------------------------------------------------
// Workspace layout (bytes from d_ws):
//   [ 0,16M)  q   bf16 [64][2048][64]   (pre-scaled by 0.125)
//   [16,32M)  k   bf16 [64][2048][64]
//   [32,48M)  v   bf16 [64][64][2048]   (transposed: [bh][d][t])
//   [48,64M)  attn bf16 [8192][1024]
//   [64,70M)  wt_qkv bf16 [3072][1024]
//   [70,72M)  wt_out bf16 [1024][1024]
// ---------------------------------------------------------------------------
extern "C" void kernel_launch(void* const* d_in, const int* in_sizes, int n_in,
                              void* d_out, int out_size, void* d_ws, size_t ws_size,
                              hipStream_t stream)
{
    const float* x     = (const float*)d_in[0];
    const float* w_qkv = (const float*)d_in[1];
    const float* w_out = (const float*)d_in[2];
    float* out = (float*)d_out;

    char* ws = (char*)d_ws;
    bf16* qb     = (bf16*)(ws);
    bf16* kb     = (bf16*)(ws + (size_t)16 * 1024 * 1024);
    bf16* vb     = (bf16*)(ws + (size_t)32 * 1024 * 1024);
    bf16* attnb  = (bf16*)(ws + (size_t)48 * 1024 * 1024);
    bf16* wtqkv  = (bf16*)(ws + (size_t)64 * 1024 * 1024);
    bf16* wtout  = (bf16*)(ws + (size_t)70 * 1024 * 1024);

    transpose_f32_to_bf16<<<dim3(N1_/32, C_/32), 256, 0, stream>>>(w_qkv, wtqkv, C_, N1_);
    transpose_f32_to_bf16<<<dim3(C_/32,  C_/32), 256, 0, stream>>>(w_out, wtout, C_, C_);

    gemm_bt<1, true><<<dim3(N1_/128, M_/128), 256, 0, stream>>>(
        (const void*)x, wtqkv, nullptr, N1_, C_, qb, kb, vb);

    attn_fused<<<dim3(T_/128, BH_), 256, 0, stream>>>(qb, kb, vb, attnb);

    gemm_bt<0, false><<<dim3(C_/128, M_/128), 256, 0, stream>>>(
        (const void*)attnb, wtout, out, C_, C_, nullptr, nullptr, nullptr);
}